// Round 15
// baseline (367.378 us; speedup 1.0000x reference)
//
#include <hip/hip_runtime.h>
#include <math.h>

#define NN 50000
#define NE 800000
#define NB 64
#define IND 773
#define MPAD 50048
#define SCAN_B 196   // ceil(NN/256)

typedef __attribute__((ext_vector_type(8))) short short8_t;
typedef __attribute__((ext_vector_type(4))) float f32x4;
typedef __attribute__((ext_vector_type(2))) float f32x2;

__device__ __forceinline__ float lrelu(float x) { return x > 0.f ? x : 0.2f * x; }
__device__ __forceinline__ short f2b(float f) {
    unsigned u = __float_as_uint(f);
    unsigned r = (u + 0x7fffu + ((u >> 16) & 1u)) >> 16;  // RNE
    return (short)r;
}
__device__ __forceinline__ float b2f(short s) {
    return __uint_as_float(((unsigned)(unsigned short)s) << 16);
}
__device__ __forceinline__ unsigned char enc8(float v) {
    return (unsigned char)(__builtin_amdgcn_cvt_pk_fp8_f32(v, v, 0, false) & 0xff);
}
__device__ __forceinline__ unsigned pack4fp8(float a, float b, float c, float d) {
    unsigned w = 0;
    w = __builtin_amdgcn_cvt_pk_fp8_f32(a, b, w, false);
    w = __builtin_amdgcn_cvt_pk_fp8_f32(c, d, w, true);
    return w;
}
__device__ __forceinline__ void dec4(unsigned w, float* v) {
    f32x2 lo = __builtin_amdgcn_cvt_pk_f32_fp8((int)w, false);
    f32x2 hi = __builtin_amdgcn_cvt_pk_f32_fp8((int)w, true);
    v[0] = lo[0]; v[1] = lo[1]; v[2] = hi[0]; v[3] = hi[1];
}
__device__ __forceinline__ void dec2(unsigned w, float* v) {
    f32x2 lo = __builtin_amdgcn_cvt_pk_f32_fp8((int)w, false);
    v[0] = lo[0]; v[1] = lo[1];
}

#define GLOAD16(g, l) __builtin_amdgcn_global_load_lds(                         \
    (const __attribute__((address_space(1))) void*)(g),                         \
    (__attribute__((address_space(3))) void*)(l), 16, 0, 0)

// ---------------- GEMM1 v2: A direct-to-register (no A-LDS), B-only LDS dbuf ----------------
// 16 waves/block (1024 thr): wave = 16-row strip x 128-col half. A frag = lane's own
// 8 consecutive fp32 of one x row (frag layout row=l&15, k=(l>>4)*8+j) -> reg, no barrier.
__global__ __launch_bounds__(1024) void gemm_a(const float* __restrict__ X,
                                               const short* __restrict__ Bt,
                                               const float* __restrict__ bias,
                                               unsigned char* __restrict__ C8) {
    const int K = 800, N = 256, NT = 25;
    __shared__ short Bs[2][256 * 32];   // 2 x 16 KB
    const int t = threadIdx.x;
    const int w = t >> 6, l = t & 63;
    const int l15 = l & 15, lh = l >> 4;
    const int bm = blockIdx.x * 128;
    const int strip = (w & 7) * 16;   // A-row strip within tile
    const int ch = (w >> 3) * 128;    // output col half
    const int arow = bm + strip + l15;
    const bool rowok = arow < NN;
    const float* xrow = X + (size_t)arow * IND;
    const short* bG = Bt + (size_t)(t >> 2) * K + (t & 3) * 8;

    f32x4 acc[8];
#pragma unroll
    for (int i = 0; i < 8; ++i) acc[i] = (f32x4){0.f, 0.f, 0.f, 0.f};

    short8_t rA0, rA1;
    auto loadA = [&](int it, short8_t& r) {
        int gk = it * 32 + lh * 8;
        if (rowok && gk + 7 < IND) {
            float4 v0 = *(const float4*)(xrow + gk);
            float4 v1 = *(const float4*)(xrow + gk + 4);
            r[0] = f2b(v0.x); r[1] = f2b(v0.y); r[2] = f2b(v0.z); r[3] = f2b(v0.w);
            r[4] = f2b(v1.x); r[5] = f2b(v1.y); r[6] = f2b(v1.z); r[7] = f2b(v1.w);
        } else {
#pragma unroll
            for (int j = 0; j < 8; ++j)
                r[j] = (rowok && gk + j < IND) ? f2b(xrow[gk + j]) : (short)0;
        }
    };
    auto stageB = [&](int buf, int it) {
        GLOAD16(bG + it * 32, &Bs[buf][w * 512]);  // 1024 thr x 16B = 16KB tile
    };

#define GAITER(IT, CC, RCUR)                                                            \
    {                                                                                   \
        _Pragma("unroll")                                                               \
        for (int ni = 0; ni < 8; ++ni) {                                                \
            short8_t bf = *(const short8_t*)&Bs[CC][(ch + ni * 16 + l15) * 32 + lh * 8];\
            acc[ni] = __builtin_amdgcn_mfma_f32_16x16x32_bf16(RCUR, bf, acc[ni], 0, 0, 0); \
        }                                                                               \
        __syncthreads();                                                                \
        if ((IT) + 2 < NT) { loadA((IT) + 2, RCUR); stageB(CC, (IT) + 2); }             \
    }

    // prologue: B(0),B(1) staged; A(0),A(1) in regs
    loadA(0, rA0);
    stageB(0, 0);
    stageB(1, 1);
    loadA(1, rA1);
    __syncthreads();

    for (int it = 0; it < NT - 1; it += 2) {
        GAITER(it, 0, rA0);
        GAITER(it + 1, 1, rA1);
    }
    GAITER(NT - 1, 0, rA0);  // it = 24
#undef GAITER

    // epilogue: relu(acc+bias) -> fp8, LDS repack (Bs = 32KB = 128x256), coalesced stores
    char* R = (char*)Bs;
#pragma unroll
    for (int ni = 0; ni < 8; ++ni) {
#pragma unroll
        for (int r = 0; r < 4; ++r) {
            int rloc = strip + lh * 4 + r;
            int gcol = ch + ni * 16 + l15;
            float v = fmaxf(acc[ni][r] + bias[gcol], 0.f);
            R[rloc * 256 + gcol] = (char)enc8(v);
        }
    }
    __syncthreads();
#pragma unroll
    for (int i = 0; i < 2; ++i) {
        int idx = i * 1024 + t;
        int row = idx >> 4, cb = (idx & 15) * 16;
        int grow = bm + row;
        if (grow < NN)
            *(float4*)&C8[(size_t)grow * N + cb] = *(float4*)&R[row * 256 + cb];
    }
}

// ---------------- GEMM2: fp8 x fp8 MFMA, fused att dots (D=64), fp8 out ----------------
__global__ __launch_bounds__(256) void gemm_b(const unsigned char* __restrict__ A8,  // h0 fp8 [MPAD][256]
                                              const unsigned char* __restrict__ B8,  // Wt1 fp8 [256][256]
                                              const float* __restrict__ att_s,
                                              const float* __restrict__ att_d,
                                              unsigned char* __restrict__ C8,        // hW1 fp8 [MPAD][256]
                                              float* __restrict__ a_s,
                                              float* __restrict__ a_d) {
    const int K = 256, N = 256, NT = 8;
    __shared__ char LDS8[16384];
    const int t = threadIdx.x;
    const int w = t >> 6, l = t & 63;
    const int l15 = l & 15, lh = l >> 4;
    const int bm = blockIdx.x * 128, bn = blockIdx.y * 128;
    const int wr = (w >> 1) * 64, wc = (w & 1) * 64;

    const unsigned char* aG = A8 + (size_t)(bm + w * 32 + (l >> 1)) * K + (l & 1) * 16;
    const unsigned char* bG = B8 + (size_t)(bn + w * 32 + (l >> 1)) * K + (l & 1) * 16;

    auto stage = [&](int buf, int k0) {
        GLOAD16(aG + k0, LDS8 + buf * 4096 + w * 1024);
        GLOAD16(bG + k0, LDS8 + 8192 + buf * 4096 + w * 1024);
    };

    f32x4 acc[4][4];
#pragma unroll
    for (int i = 0; i < 4; ++i)
#pragma unroll
        for (int j = 0; j < 4; ++j) acc[i][j] = (f32x4){0.f, 0.f, 0.f, 0.f};

    stage(0, 0);
    stage(1, 32);
    __syncthreads();

    for (int it = 0; it < NT; ++it) {
        const int c = it & 1;
        long af[4], bfr[4];
#pragma unroll
        for (int mi = 0; mi < 4; ++mi)
            af[mi] = *(const long*)&LDS8[c * 4096 + (wr + mi * 16 + l15) * 32 + lh * 8];
#pragma unroll
        for (int ni = 0; ni < 4; ++ni)
            bfr[ni] = *(const long*)&LDS8[8192 + c * 4096 + (wc + ni * 16 + l15) * 32 + lh * 8];
#pragma unroll
        for (int mi = 0; mi < 4; ++mi)
#pragma unroll
            for (int ni = 0; ni < 4; ++ni)
                acc[mi][ni] = __builtin_amdgcn_mfma_f32_16x16x32_fp8_fp8(af[mi], bfr[ni], acc[mi][ni], 0, 0, 0);
        __syncthreads();
        if (it + 2 < NT) stage(c, (it + 2) * 32);
    }

    const int head = (bn + wc) >> 6;
    float sa[4], sd[4];
#pragma unroll
    for (int ni = 0; ni < 4; ++ni) {
        sa[ni] = att_s[head * 64 + ni * 16 + l15];
        sd[ni] = att_d[head * 64 + ni * 16 + l15];
    }
    char* R = LDS8;
#pragma unroll
    for (int mi = 0; mi < 4; ++mi) {
#pragma unroll
        for (int r = 0; r < 4; ++r) {
            int rloc = wr + mi * 16 + lh * 4 + r;
            int grow = bm + rloc;
            float s = acc[mi][0][r] * sa[0] + acc[mi][1][r] * sa[1] +
                      acc[mi][2][r] * sa[2] + acc[mi][3][r] * sa[3];
            float d = acc[mi][0][r] * sd[0] + acc[mi][1][r] * sd[1] +
                      acc[mi][2][r] * sd[2] + acc[mi][3][r] * sd[3];
#pragma unroll
            for (int off = 1; off < 16; off <<= 1) {
                s += __shfl_xor(s, off);
                d += __shfl_xor(d, off);
            }
            if (grow < NN && l15 == 0) { a_s[grow * 4 + head] = s; a_d[grow * 4 + head] = d; }
#pragma unroll
            for (int ni = 0; ni < 4; ++ni)
                R[rloc * 128 + wc + ni * 16 + l15] = (char)enc8(acc[mi][ni][r]);
        }
    }
    __syncthreads();
#pragma unroll
    for (int i = 0; i < 4; ++i) {
        int idx = i * 256 + t;
        int row = idx >> 3, cb = (idx & 7) * 16;
        int grow = bm + row;
        if (grow < NN)
            *(float4*)&C8[(size_t)grow * N + bn + cb] = *(float4*)&R[row * 128 + cb];
    }
}

// ---------------- GEMM3: fp8 x fp8, fused att dots (D=32), fp8 out ----------------
__global__ __launch_bounds__(256) void gemm_c(const unsigned char* __restrict__ A8,  // h1 fp8 [MPAD][256]
                                              const unsigned char* __restrict__ B8,  // Wt2 fp8 [128][256]
                                              const float* __restrict__ att_s,
                                              const float* __restrict__ att_d,
                                              unsigned char* __restrict__ C8,        // hW2 fp8 [MPAD][128]
                                              float* __restrict__ a_s,
                                              float* __restrict__ a_d) {
    const int K = 256, N = 128, NT = 8;
    __shared__ char LDS8[16384];
    const int t = threadIdx.x;
    const int w = t >> 6, l = t & 63;
    const int l15 = l & 15, lh = l >> 4;
    const int bm = blockIdx.x * 128;
    const int wr = (w >> 1) * 64, wc = (w & 1) * 64;

    const unsigned char* aG = A8 + (size_t)(bm + w * 32 + (l >> 1)) * K + (l & 1) * 16;
    const unsigned char* bG = B8 + (size_t)(w * 32 + (l >> 1)) * K + (l & 1) * 16;

    auto stage = [&](int buf, int k0) {
        GLOAD16(aG + k0, LDS8 + buf * 4096 + w * 1024);
        GLOAD16(bG + k0, LDS8 + 8192 + buf * 4096 + w * 1024);
    };

    f32x4 acc[4][4];
#pragma unroll
    for (int i = 0; i < 4; ++i)
#pragma unroll
        for (int j = 0; j < 4; ++j) acc[i][j] = (f32x4){0.f, 0.f, 0.f, 0.f};

    stage(0, 0);
    stage(1, 32);
    __syncthreads();

    for (int it = 0; it < NT; ++it) {
        const int c = it & 1;
        long af[4], bfr[4];
#pragma unroll
        for (int mi = 0; mi < 4; ++mi)
            af[mi] = *(const long*)&LDS8[c * 4096 + (wr + mi * 16 + l15) * 32 + lh * 8];
#pragma unroll
        for (int ni = 0; ni < 4; ++ni)
            bfr[ni] = *(const long*)&LDS8[8192 + c * 4096 + (wc + ni * 16 + l15) * 32 + lh * 8];
#pragma unroll
        for (int mi = 0; mi < 4; ++mi)
#pragma unroll
            for (int ni = 0; ni < 4; ++ni)
                acc[mi][ni] = __builtin_amdgcn_mfma_f32_16x16x32_fp8_fp8(af[mi], bfr[ni], acc[mi][ni], 0, 0, 0);
        __syncthreads();
        if (it + 2 < NT) stage(c, (it + 2) * 32);
    }

    const int h0 = wc >> 5;
    float sa[4], sd[4];
#pragma unroll
    for (int ni = 0; ni < 4; ++ni) {
        int idx = (h0 + (ni >> 1)) * 32 + (ni & 1) * 16 + l15;
        sa[ni] = att_s[idx];
        sd[ni] = att_d[idx];
    }
    char* R = LDS8;
#pragma unroll
    for (int mi = 0; mi < 4; ++mi) {
#pragma unroll
        for (int r = 0; r < 4; ++r) {
            int rloc = wr + mi * 16 + lh * 4 + r;
            int grow = bm + rloc;
            float s0 = acc[mi][0][r] * sa[0] + acc[mi][1][r] * sa[1];
            float s1 = acc[mi][2][r] * sa[2] + acc[mi][3][r] * sa[3];
            float d0 = acc[mi][0][r] * sd[0] + acc[mi][1][r] * sd[1];
            float d1 = acc[mi][2][r] * sd[2] + acc[mi][3][r] * sd[3];
#pragma unroll
            for (int off = 1; off < 16; off <<= 1) {
                s0 += __shfl_xor(s0, off); s1 += __shfl_xor(s1, off);
                d0 += __shfl_xor(d0, off); d1 += __shfl_xor(d1, off);
            }
            if (grow < NN && l15 == 0) {
                a_s[grow * 4 + h0] = s0; a_s[grow * 4 + h0 + 1] = s1;
                a_d[grow * 4 + h0] = d0; a_d[grow * 4 + h0 + 1] = d1;
            }
#pragma unroll
            for (int ni = 0; ni < 4; ++ni)
                R[rloc * 128 + wc + ni * 16 + l15] = (char)enc8(acc[mi][ni][r]);
        }
    }
    __syncthreads();
#pragma unroll
    for (int i = 0; i < 4; ++i) {
        int idx = i * 256 + t;
        int row = idx >> 3, cb = (idx & 7) * 16;
        int grow = bm + row;
        if (grow < NN)
            *(float4*)&C8[(size_t)grow * N + cb] = *(float4*)&R[row * 128 + cb];
    }
}

// ---------------- fused prep: W_in->bf16T, W1/W2->fp8T, deg+emb zero ----------------
__global__ __launch_bounds__(256) void k_prep(const float* __restrict__ W_in,
                                              const float* __restrict__ W1,
                                              const float* __restrict__ W2,
                                              short* __restrict__ Wt_in,
                                              unsigned char* __restrict__ Wt1,
                                              unsigned char* __restrict__ Wt2,
                                              int* __restrict__ deg,
                                              float* __restrict__ emb) {
    int b = blockIdx.x;
    const float* W; int K, N, Kp, kb, nb, fp8;
    short* Wts = nullptr; unsigned char* Wt8 = nullptr;
    if (b < 200)      { W = W_in; Wts = Wt_in; fp8 = 0; K = IND; N = 256; Kp = 800; kb = (b % 25) * 32; nb = (b / 25) * 32; }
    else if (b < 264) { b -= 200; W = W1; Wt8 = Wt1; fp8 = 1; K = 256; N = 256; Kp = 256; kb = (b % 8) * 32; nb = (b / 8) * 32; }
    else if (b < 296) { b -= 264; W = W2; Wt8 = Wt2; fp8 = 1; K = 256; N = 128; Kp = 256; kb = (b % 8) * 32; nb = (b / 8) * 32; }
    else {
        int i = (b - 296) * 256 + threadIdx.x;
        if (i < NN) deg[i] = 0;
        if (i < NB * 128) emb[i] = 0.f;
        return;
    }
    __shared__ float tile[32][33];
    int tx = threadIdx.x & 31, ty = threadIdx.x >> 5;
#pragma unroll
    for (int r = 0; r < 32; r += 8) {
        int k = kb + ty + r;
        tile[ty + r][tx] = (k < K) ? W[(size_t)k * N + nb + tx] : 0.f;
    }
    __syncthreads();
#pragma unroll
    for (int r = 0; r < 32; r += 8) {
        int n = nb + ty + r, k = kb + tx;
        float v = tile[tx][ty + r];
        if (fp8) Wt8[(size_t)n * Kp + k] = enc8(v);
        else     Wts[(size_t)n * Kp + k] = f2b(v);
    }
}

// ---------------- CSR build ----------------
__global__ void k_hist(const int* __restrict__ ei, int* __restrict__ deg) {
    int e = blockIdx.x * 256 + threadIdx.x;
    if (e >= NE) return;
    atomicAdd(&deg[ei[NE + e]], 1);
}

__global__ __launch_bounds__(256) void k_bsum(const int* __restrict__ deg,
                                              int* __restrict__ bsum) {
    int i = blockIdx.x * 256 + threadIdx.x;
    int v = (i < NN) ? deg[i] : 0;
#pragma unroll
    for (int off = 32; off; off >>= 1) v += __shfl_down(v, off);
    __shared__ int ws[4];
    if ((threadIdx.x & 63) == 0) ws[threadIdx.x >> 6] = v;
    __syncthreads();
    if (threadIdx.x == 0) bsum[blockIdx.x] = ws[0] + ws[1] + ws[2] + ws[3];
}

__global__ __launch_bounds__(256) void k_scan3(const int* __restrict__ deg,
                                               const int* __restrict__ bsum,
                                               int* __restrict__ rowp,
                                               int* __restrict__ cursor) {
    int b = blockIdx.x;
    int i = b * 256 + threadIdx.x;
    int d = (i < NN) ? deg[i] : 0;
    __shared__ int sb[SCAN_B];
    if (threadIdx.x < SCAN_B) sb[threadIdx.x] = bsum[threadIdx.x];
    int v = d;
    int lane = threadIdx.x & 63, wid = threadIdx.x >> 6;
#pragma unroll
    for (int off = 1; off < 64; off <<= 1) {
        int u = __shfl_up(v, off);
        if (lane >= off) v += u;
    }
    __shared__ int ws[4];
    if (lane == 63) ws[wid] = v;
    __syncthreads();
    int add = 0;
    for (int q = 0; q < b; ++q) add += sb[q];
    for (int wq = 0; wq < wid; ++wq) add += ws[wq];
    int excl = add + v - d;
    if (i < NN) { rowp[i] = excl; cursor[i] = excl; }
    if (i == NN - 1) rowp[NN] = excl + d;
}

__global__ void k_scatter(const int* __restrict__ ei, int* __restrict__ cursor,
                          int* __restrict__ colidx) {
    int e = blockIdx.x * 256 + threadIdx.x;
    if (e >= NE) return;
    int s = ei[e], d = ei[NE + e];
    int pos = atomicAdd(&cursor[d], 1);
    colidx[pos] = s;
}

// ---------------- fused GAT aggregation, fp8 gather; OUT8: fp8 or bf16 out ----------------
template<int HD, int OUT8>
__global__ __launch_bounds__(256) void gat_agg(const unsigned char* __restrict__ hW8,
                                               const float* __restrict__ a_s,
                                               const float* __restrict__ a_d,
                                               const int* __restrict__ row_ptr,
                                               const int* __restrict__ colidx,
                                               const float* __restrict__ bias,
                                               void* __restrict__ outp) {
    const int CPL = HD / 64;
    int node = blockIdx.x * 4 + (threadIdx.x >> 6);
    int lane = threadIdx.x & 63;
    if (node >= NN) return;
    int h = lane >> 4;
    int start = row_ptr[node], end = row_ptr[node + 1];
    float adst = a_d[node * 4 + h];
    float eself = lrelu(a_s[node * 4 + h] + adst);

    float z = 1.f;
    float acc[CPL];
    {
        const unsigned char* row = hW8 + (size_t)node * HD + lane * CPL;
        if (CPL == 4) dec4(*(const unsigned*)row, acc);
        else          dec2(*(const unsigned short*)row, acc);
    }
    for (int e = start; e < end; e += 8) {
        int sidx[8];
        float xs[8], ex[8];
#pragma unroll
        for (int q = 0; q < 8; ++q) {
            int ee = e + q;
            sidx[q] = colidx[ee < end ? ee : end - 1];
        }
#pragma unroll
        for (int q = 0; q < 8; ++q) xs[q] = a_s[sidx[q] * 4 + h];
        float v[8][CPL];
        if (CPL == 4) {
#pragma unroll
            for (int q = 0; q < 8; ++q)
                dec4(*(const unsigned*)(hW8 + (size_t)sidx[q] * HD + lane * 4), v[q]);
        } else {
#pragma unroll
            for (int q = 0; q < 8; ++q)
                dec2(*(const unsigned short*)(hW8 + (size_t)sidx[q] * HD + lane * 2), v[q]);
        }
#pragma unroll
        for (int q = 0; q < 8; ++q) {
            float wq = __expf(lrelu(xs[q] + adst) - eself);
            ex[q] = (e + q < end) ? wq : 0.f;
        }
#pragma unroll
        for (int q = 0; q < 8; ++q) z += ex[q];
#pragma unroll
        for (int j = 0; j < CPL; ++j) {
            float a = 0.f;
#pragma unroll
            for (int q = 0; q < 8; ++q) a += ex[q] * v[q][j];
            acc[j] += a;
        }
    }
    float inv = 1.f / z;
    float o[CPL];
#pragma unroll
    for (int j = 0; j < CPL; ++j)
        o[j] = fmaxf(acc[j] * inv + bias[lane * CPL + j], 0.f);
    if (OUT8) {
        unsigned* orow = (unsigned*)((unsigned char*)outp + (size_t)node * HD + lane * 4);
        *orow = pack4fp8(o[0], o[1], (CPL == 4 ? o[2] : 0.f), (CPL == 4 ? o[3] : 0.f));
    } else {
        short* orow = (short*)outp + (size_t)node * HD + lane * CPL;
#pragma unroll
        for (int j = 0; j < CPL; ++j) orow[j] = f2b(o[j]);
    }
}

// ---------------- pooling: partial sums (256 blocks) + head ----------------
__global__ __launch_bounds__(128) void k_pool(const short* __restrict__ h2,
                                              const int* __restrict__ batch,
                                              float* __restrict__ emb) {
    int b = blockIdx.x >> 2;
    int chunk = blockIdx.x & 3;
    int t = threadIdx.x;
    int lo = 0, hi = NN;
    while (lo < hi) { int mid = (lo + hi) >> 1; if (batch[mid] < b) lo = mid + 1; else hi = mid; }
    int start = lo;
    lo = 0; hi = NN;
    while (lo < hi) { int mid = (lo + hi) >> 1; if (batch[mid] < b + 1) lo = mid + 1; else hi = mid; }
    int end = lo;
    float s = 0.f;
    for (int n = start + chunk; n < end; n += 4) s += b2f(h2[(size_t)n * 128 + t]);
    atomicAdd(&emb[b * 128 + t], s);
}

__global__ __launch_bounds__(128) void k_head(const float* __restrict__ emb,
                                              const int* __restrict__ batch,
                                              const float* __restrict__ W_cls,
                                              const float* __restrict__ b_cls,
                                              const float* __restrict__ W_conf,
                                              const float* __restrict__ b_conf,
                                              float* __restrict__ out) {
    int b = blockIdx.x;
    int t = threadIdx.x;
    int lo = 0, hi = NN;
    while (lo < hi) { int mid = (lo + hi) >> 1; if (batch[mid] < b) lo = mid + 1; else hi = mid; }
    int start = lo;
    lo = 0; hi = NN;
    while (lo < hi) { int mid = (lo + hi) >> 1; if (batch[mid] < b + 1) lo = mid + 1; else hi = mid; }
    int end = lo;
    __shared__ float se[128];
    se[t] = emb[b * 128 + t] / fmaxf((float)(end - start), 1.f);
    __syncthreads();
    if (t == 0) {
        float v = b_cls[0];
        for (int c = 0; c < 128; ++c) v += se[c] * W_cls[c * 2 + 0];
        out[b * 2 + 0] = v;
    } else if (t == 1) {
        float v = b_cls[1];
        for (int c = 0; c < 128; ++c) v += se[c] * W_cls[c * 2 + 1];
        out[b * 2 + 1] = v;
    } else if (t == 2) {
        float v = b_conf[0];
        for (int c = 0; c < 128; ++c) v += se[c] * W_conf[c];
        out[128 + b] = 1.f / (1.f + expf(-v));
    }
}

extern "C" void kernel_launch(void* const* d_in, const int* in_sizes, int n_in,
                              void* d_out, int out_size, void* d_ws, size_t ws_size,
                              hipStream_t stream) {
    const float* x        = (const float*)d_in[0];
    const int*   ei       = (const int*)d_in[1];
    const int*   batch    = (const int*)d_in[2];
    const float* W_in     = (const float*)d_in[3];
    const float* b_in     = (const float*)d_in[4];
    const float* W1       = (const float*)d_in[5];
    const float* att_src1 = (const float*)d_in[6];
    const float* att_dst1 = (const float*)d_in[7];
    const float* b1       = (const float*)d_in[8];
    const float* W2       = (const float*)d_in[9];
    const float* att_src2 = (const float*)d_in[10];
    const float* att_dst2 = (const float*)d_in[11];
    const float* b2       = (const float*)d_in[12];
    const float* W_cls    = (const float*)d_in[13];
    const float* b_cls    = (const float*)d_in[14];
    const float* W_conf   = (const float*)d_in[15];
    const float* b_conf   = (const float*)d_in[16];
    float* out = (float*)d_out;

    char* ws = (char*)d_ws;
    unsigned char* h0  = (unsigned char*)(ws + 0);          // [MPAD][256] fp8
    unsigned char* hW1 = (unsigned char*)(ws + 12812288);   // [MPAD][256] fp8
    unsigned char* h1  = (unsigned char*)(ws + 25624576);   // [MPAD][256] fp8
    unsigned char* hW2 = (unsigned char*)(ws + 38436864);   // [MPAD][128] fp8
    short*         h2  = (short*)(ws + 44843008);           // [MPAD][128] bf16
    size_t base = 57655296;
    short*         Wt_in = (short*)(ws + base);                   // [256][800] bf16
    unsigned char* Wt1   = (unsigned char*)(ws + base + 409600);  // [256][256] fp8
    unsigned char* Wt2   = (unsigned char*)(ws + base + 475136);  // [128][256] fp8
    float* a_s1  = (float*)(ws + base + 507904);
    float* a_d1  = (float*)(ws + base + 1307904);
    float* emb   = (float*)(ws + base + 2107904);   // [64][128]
    int*   deg    = (int*)(ws + base + 2140672);
    int*   rowp   = (int*)(ws + base + 2340672);
    int*   cursor = (int*)(ws + base + 2540736);
    int*   colidx = (int*)(ws + base + 2740736);    // [800000]
    int*   bsum   = (int*)(ws + base + 5940736);

    // prep: weight transposes (bf16 + fp8) + deg/emb zero
    k_prep<<<296 + SCAN_B, 256, 0, stream>>>(W_in, W1, W2, Wt_in, Wt1, Wt2, deg, emb);
    // CSR build
    k_hist<<<NE / 256, 256, 0, stream>>>(ei, deg);
    k_bsum<<<SCAN_B, 256, 0, stream>>>(deg, bsum);
    k_scan3<<<SCAN_B, 256, 0, stream>>>(deg, bsum, rowp, cursor);
    k_scatter<<<NE / 256, 256, 0, stream>>>(ei, cursor, colidx);

    // h0(fp8) = relu(x @ W_in + b_in)  (A direct-to-register v2)
    gemm_a<<<391, 1024, 0, stream>>>(x, Wt_in, b_in, h0);
    // hW1(fp8) = h0 @ W1 (fp8 MFMA), att dots fused
    gemm_b<<<dim3(391, 2), 256, 0, stream>>>(h0, Wt1, att_src1, att_dst1, hW1, a_s1, a_d1);
    gat_agg<256, 1><<<12500, 256, 0, stream>>>(hW1, a_s1, a_d1, rowp, colidx, b1, h1);
    // hW2(fp8) = h1 @ W2 (fp8 MFMA), att dots fused
    gemm_c<<<391, 256, 0, stream>>>(h1, Wt2, att_src2, att_dst2, hW2, a_s1, a_d1);
    gat_agg<128, 0><<<12500, 256, 0, stream>>>(hW2, a_s1, a_d1, rowp, colidx, b2, h2);
    // pool + heads
    k_pool<<<NB * 4, 128, 0, stream>>>(h2, batch, emb);
    k_head<<<NB, 128, 0, stream>>>(emb, batch, W_cls, b_cls, W_conf, b_conf, out);
}

// Round 16
// 338.784 us; speedup vs baseline: 1.0844x; 1.0844x over previous
//
#include <hip/hip_runtime.h>
#include <math.h>

#define NN 50000
#define NE 800000
#define NB 64
#define IND 773
#define MPAD 50048
#define SCAN_B 196   // ceil(NN/256)

typedef __attribute__((ext_vector_type(8))) short short8_t;
typedef __attribute__((ext_vector_type(4))) float f32x4;
typedef __attribute__((ext_vector_type(2))) float f32x2;

__device__ __forceinline__ float lrelu(float x) { return x > 0.f ? x : 0.2f * x; }
__device__ __forceinline__ short f2b(float f) {
    unsigned u = __float_as_uint(f);
    unsigned r = (u + 0x7fffu + ((u >> 16) & 1u)) >> 16;  // RNE
    return (short)r;
}
__device__ __forceinline__ float b2f(short s) {
    return __uint_as_float(((unsigned)(unsigned short)s) << 16);
}
__device__ __forceinline__ unsigned char enc8(float v) {
    return (unsigned char)(__builtin_amdgcn_cvt_pk_fp8_f32(v, v, 0, false) & 0xff);
}
__device__ __forceinline__ unsigned pack4fp8(float a, float b, float c, float d) {
    unsigned w = 0;
    w = __builtin_amdgcn_cvt_pk_fp8_f32(a, b, w, false);
    w = __builtin_amdgcn_cvt_pk_fp8_f32(c, d, w, true);
    return w;
}
__device__ __forceinline__ void dec4(unsigned w, float* v) {
    f32x2 lo = __builtin_amdgcn_cvt_pk_f32_fp8((int)w, false);
    f32x2 hi = __builtin_amdgcn_cvt_pk_f32_fp8((int)w, true);
    v[0] = lo[0]; v[1] = lo[1]; v[2] = hi[0]; v[3] = hi[1];
}
__device__ __forceinline__ void dec2(unsigned w, float* v) {
    f32x2 lo = __builtin_amdgcn_cvt_pk_f32_fp8((int)w, false);
    v[0] = lo[0]; v[1] = lo[1];
}

#define GLOAD16(g, l) __builtin_amdgcn_global_load_lds(                         \
    (const __attribute__((address_space(1))) void*)(g),                         \
    (__attribute__((address_space(3))) void*)(l), 16, 0, 0)

// ---------------- GEMM1 (frozen round-13 structure, 91us floor), fp8 h0 output ----------------
__global__ __launch_bounds__(512) void gemm_a(const float* __restrict__ X,
                                              const short* __restrict__ Bt,
                                              const float* __restrict__ bias,
                                              unsigned char* __restrict__ C8) {
    const int K = 800, N = 256, NT = 25;
    __shared__ short As[2][128 * 32];
    __shared__ short Bs[2][256 * 32];
    const int t = threadIdx.x;
    const int w = t >> 6, l = t & 63;
    const int l15 = l & 15, lh = l >> 4;
    const int bm = blockIdx.x * 128;
    const int wr = (w >> 2) * 64, wc = (w & 3) * 64;
    const int arow = t >> 2, acb = (t & 3) * 8;
    const int gm = bm + arow;
    const bool rowok = gm < NN;
    const float* xrow = X + (size_t)gm * IND;
    const short* bG = Bt + (size_t)(t >> 2) * K + (t & 3) * 8;

    f32x4 acc[4][4];
#pragma unroll
    for (int i = 0; i < 4; ++i)
#pragma unroll
        for (int j = 0; j < 4; ++j) acc[i][j] = (f32x4){0.f, 0.f, 0.f, 0.f};

    short8_t rA;
    auto loadA = [&](int it) {
        int gk = it * 32 + acb;
        if (rowok && gk + 7 < IND) {
            float4 v0 = *(const float4*)(xrow + gk);
            float4 v1 = *(const float4*)(xrow + gk + 4);
            rA[0] = f2b(v0.x); rA[1] = f2b(v0.y); rA[2] = f2b(v0.z); rA[3] = f2b(v0.w);
            rA[4] = f2b(v1.x); rA[5] = f2b(v1.y); rA[6] = f2b(v1.z); rA[7] = f2b(v1.w);
        } else {
#pragma unroll
            for (int j = 0; j < 8; ++j)
                rA[j] = (rowok && gk + j < IND) ? f2b(xrow[gk + j]) : (short)0;
        }
    };
    auto stageB = [&](int buf, int it) {
        GLOAD16(bG + it * 32, &Bs[buf][w * 512]);
        GLOAD16(bG + (size_t)128 * K + it * 32, &Bs[buf][128 * 32 + w * 512]);
    };

    loadA(0);
    stageB(0, 0);
    stageB(1, 1);
    *(short8_t*)&As[0][arow * 32 + acb] = rA;
    loadA(1);
    __syncthreads();

    for (int it = 0; it < NT; ++it) {
        const int c = it & 1, n = c ^ 1;
        short8_t af[4], bfr[4];
#pragma unroll
        for (int mi = 0; mi < 4; ++mi)
            af[mi] = *(const short8_t*)&As[c][(wr + mi * 16 + l15) * 32 + lh * 8];
#pragma unroll
        for (int ni = 0; ni < 4; ++ni)
            bfr[ni] = *(const short8_t*)&Bs[c][(wc + ni * 16 + l15) * 32 + lh * 8];
        if (it + 1 < NT) *(short8_t*)&As[n][arow * 32 + acb] = rA;
#pragma unroll
        for (int mi = 0; mi < 4; ++mi)
#pragma unroll
            for (int ni = 0; ni < 4; ++ni)
                acc[mi][ni] = __builtin_amdgcn_mfma_f32_16x16x32_bf16(af[mi], bfr[ni], acc[mi][ni], 0, 0, 0);
        __syncthreads();
        if (it + 2 < NT) {
            loadA(it + 2);
            stageB(c, it + 2);
        }
    }

    // epilogue: relu(acc+bias) -> fp8 via Bs repack (32KB = 128x256), coalesced stores
    char* R = (char*)Bs;
#pragma unroll
    for (int mi = 0; mi < 4; ++mi) {
#pragma unroll
        for (int r = 0; r < 4; ++r) {
            int rloc = wr + mi * 16 + lh * 4 + r;
#pragma unroll
            for (int ni = 0; ni < 4; ++ni) {
                int gcol = wc + ni * 16 + l15;
                float v = fmaxf(acc[mi][ni][r] + bias[gcol], 0.f);
                R[rloc * 256 + gcol] = (char)enc8(v);
            }
        }
    }
    __syncthreads();
#pragma unroll
    for (int i = 0; i < 4; ++i) {
        int idx = i * 512 + t;
        int row = idx >> 4, cb = (idx & 15) * 16;
        int grow = bm + row;
        if (grow < NN)
            *(float4*)&C8[(size_t)grow * N + cb] = *(float4*)&R[row * 256 + cb];
    }
}

// ---------------- GEMM2: fp8 x fp8 MFMA, fused att dots (D=64), fp8 out ----------------
__global__ __launch_bounds__(256) void gemm_b(const unsigned char* __restrict__ A8,  // h0 fp8 [MPAD][256]
                                              const unsigned char* __restrict__ B8,  // Wt1 fp8 [256][256]
                                              const float* __restrict__ att_s,
                                              const float* __restrict__ att_d,
                                              unsigned char* __restrict__ C8,        // hW1 fp8 [MPAD][256]
                                              float* __restrict__ a_s,
                                              float* __restrict__ a_d) {
    const int K = 256, N = 256, NT = 8;
    __shared__ char LDS8[16384];
    const int t = threadIdx.x;
    const int w = t >> 6, l = t & 63;
    const int l15 = l & 15, lh = l >> 4;
    const int bm = blockIdx.x * 128, bn = blockIdx.y * 128;
    const int wr = (w >> 1) * 64, wc = (w & 1) * 64;

    const unsigned char* aG = A8 + (size_t)(bm + w * 32 + (l >> 1)) * K + (l & 1) * 16;
    const unsigned char* bG = B8 + (size_t)(bn + w * 32 + (l >> 1)) * K + (l & 1) * 16;

    auto stage = [&](int buf, int k0) {
        GLOAD16(aG + k0, LDS8 + buf * 4096 + w * 1024);
        GLOAD16(bG + k0, LDS8 + 8192 + buf * 4096 + w * 1024);
    };

    f32x4 acc[4][4];
#pragma unroll
    for (int i = 0; i < 4; ++i)
#pragma unroll
        for (int j = 0; j < 4; ++j) acc[i][j] = (f32x4){0.f, 0.f, 0.f, 0.f};

    stage(0, 0);
    stage(1, 32);
    __syncthreads();

    for (int it = 0; it < NT; ++it) {
        const int c = it & 1;
        long af[4], bfr[4];
#pragma unroll
        for (int mi = 0; mi < 4; ++mi)
            af[mi] = *(const long*)&LDS8[c * 4096 + (wr + mi * 16 + l15) * 32 + lh * 8];
#pragma unroll
        for (int ni = 0; ni < 4; ++ni)
            bfr[ni] = *(const long*)&LDS8[8192 + c * 4096 + (wc + ni * 16 + l15) * 32 + lh * 8];
#pragma unroll
        for (int mi = 0; mi < 4; ++mi)
#pragma unroll
            for (int ni = 0; ni < 4; ++ni)
                acc[mi][ni] = __builtin_amdgcn_mfma_f32_16x16x32_fp8_fp8(af[mi], bfr[ni], acc[mi][ni], 0, 0, 0);
        __syncthreads();
        if (it + 2 < NT) stage(c, (it + 2) * 32);
    }

    const int head = (bn + wc) >> 6;
    float sa[4], sd[4];
#pragma unroll
    for (int ni = 0; ni < 4; ++ni) {
        sa[ni] = att_s[head * 64 + ni * 16 + l15];
        sd[ni] = att_d[head * 64 + ni * 16 + l15];
    }
    char* R = LDS8;
#pragma unroll
    for (int mi = 0; mi < 4; ++mi) {
#pragma unroll
        for (int r = 0; r < 4; ++r) {
            int rloc = wr + mi * 16 + lh * 4 + r;
            int grow = bm + rloc;
            float s = acc[mi][0][r] * sa[0] + acc[mi][1][r] * sa[1] +
                      acc[mi][2][r] * sa[2] + acc[mi][3][r] * sa[3];
            float d = acc[mi][0][r] * sd[0] + acc[mi][1][r] * sd[1] +
                      acc[mi][2][r] * sd[2] + acc[mi][3][r] * sd[3];
#pragma unroll
            for (int off = 1; off < 16; off <<= 1) {
                s += __shfl_xor(s, off);
                d += __shfl_xor(d, off);
            }
            if (grow < NN && l15 == 0) { a_s[grow * 4 + head] = s; a_d[grow * 4 + head] = d; }
#pragma unroll
            for (int ni = 0; ni < 4; ++ni)
                R[rloc * 128 + wc + ni * 16 + l15] = (char)enc8(acc[mi][ni][r]);
        }
    }
    __syncthreads();
#pragma unroll
    for (int i = 0; i < 4; ++i) {
        int idx = i * 256 + t;
        int row = idx >> 3, cb = (idx & 7) * 16;
        int grow = bm + row;
        if (grow < NN)
            *(float4*)&C8[(size_t)grow * N + bn + cb] = *(float4*)&R[row * 128 + cb];
    }
}

// ---------------- GEMM3: fp8 x fp8, fused att dots (D=32), fp8 out ----------------
__global__ __launch_bounds__(256) void gemm_c(const unsigned char* __restrict__ A8,  // h1 fp8 [MPAD][256]
                                              const unsigned char* __restrict__ B8,  // Wt2 fp8 [128][256]
                                              const float* __restrict__ att_s,
                                              const float* __restrict__ att_d,
                                              unsigned char* __restrict__ C8,        // hW2 fp8 [MPAD][128]
                                              float* __restrict__ a_s,
                                              float* __restrict__ a_d) {
    const int K = 256, N = 128, NT = 8;
    __shared__ char LDS8[16384];
    const int t = threadIdx.x;
    const int w = t >> 6, l = t & 63;
    const int l15 = l & 15, lh = l >> 4;
    const int bm = blockIdx.x * 128;
    const int wr = (w >> 1) * 64, wc = (w & 1) * 64;

    const unsigned char* aG = A8 + (size_t)(bm + w * 32 + (l >> 1)) * K + (l & 1) * 16;
    const unsigned char* bG = B8 + (size_t)(w * 32 + (l >> 1)) * K + (l & 1) * 16;

    auto stage = [&](int buf, int k0) {
        GLOAD16(aG + k0, LDS8 + buf * 4096 + w * 1024);
        GLOAD16(bG + k0, LDS8 + 8192 + buf * 4096 + w * 1024);
    };

    f32x4 acc[4][4];
#pragma unroll
    for (int i = 0; i < 4; ++i)
#pragma unroll
        for (int j = 0; j < 4; ++j) acc[i][j] = (f32x4){0.f, 0.f, 0.f, 0.f};

    stage(0, 0);
    stage(1, 32);
    __syncthreads();

    for (int it = 0; it < NT; ++it) {
        const int c = it & 1;
        long af[4], bfr[4];
#pragma unroll
        for (int mi = 0; mi < 4; ++mi)
            af[mi] = *(const long*)&LDS8[c * 4096 + (wr + mi * 16 + l15) * 32 + lh * 8];
#pragma unroll
        for (int ni = 0; ni < 4; ++ni)
            bfr[ni] = *(const long*)&LDS8[8192 + c * 4096 + (wc + ni * 16 + l15) * 32 + lh * 8];
#pragma unroll
        for (int mi = 0; mi < 4; ++mi)
#pragma unroll
            for (int ni = 0; ni < 4; ++ni)
                acc[mi][ni] = __builtin_amdgcn_mfma_f32_16x16x32_fp8_fp8(af[mi], bfr[ni], acc[mi][ni], 0, 0, 0);
        __syncthreads();
        if (it + 2 < NT) stage(c, (it + 2) * 32);
    }

    const int h0 = wc >> 5;
    float sa[4], sd[4];
#pragma unroll
    for (int ni = 0; ni < 4; ++ni) {
        int idx = (h0 + (ni >> 1)) * 32 + (ni & 1) * 16 + l15;
        sa[ni] = att_s[idx];
        sd[ni] = att_d[idx];
    }
    char* R = LDS8;
#pragma unroll
    for (int mi = 0; mi < 4; ++mi) {
#pragma unroll
        for (int r = 0; r < 4; ++r) {
            int rloc = wr + mi * 16 + lh * 4 + r;
            int grow = bm + rloc;
            float s0 = acc[mi][0][r] * sa[0] + acc[mi][1][r] * sa[1];
            float s1 = acc[mi][2][r] * sa[2] + acc[mi][3][r] * sa[3];
            float d0 = acc[mi][0][r] * sd[0] + acc[mi][1][r] * sd[1];
            float d1 = acc[mi][2][r] * sd[2] + acc[mi][3][r] * sd[3];
#pragma unroll
            for (int off = 1; off < 16; off <<= 1) {
                s0 += __shfl_xor(s0, off); s1 += __shfl_xor(s1, off);
                d0 += __shfl_xor(d0, off); d1 += __shfl_xor(d1, off);
            }
            if (grow < NN && l15 == 0) {
                a_s[grow * 4 + h0] = s0; a_s[grow * 4 + h0 + 1] = s1;
                a_d[grow * 4 + h0] = d0; a_d[grow * 4 + h0 + 1] = d1;
            }
#pragma unroll
            for (int ni = 0; ni < 4; ++ni)
                R[rloc * 128 + wc + ni * 16 + l15] = (char)enc8(acc[mi][ni][r]);
        }
    }
    __syncthreads();
#pragma unroll
    for (int i = 0; i < 4; ++i) {
        int idx = i * 256 + t;
        int row = idx >> 3, cb = (idx & 7) * 16;
        int grow = bm + row;
        if (grow < NN)
            *(float4*)&C8[(size_t)grow * N + cb] = *(float4*)&R[row * 128 + cb];
    }
}

// ---------------- fused prep: W_in->bf16T, W1/W2->fp8T, deg+emb zero ----------------
__global__ __launch_bounds__(256) void k_prep(const float* __restrict__ W_in,
                                              const float* __restrict__ W1,
                                              const float* __restrict__ W2,
                                              short* __restrict__ Wt_in,
                                              unsigned char* __restrict__ Wt1,
                                              unsigned char* __restrict__ Wt2,
                                              int* __restrict__ deg,
                                              float* __restrict__ emb) {
    int b = blockIdx.x;
    const float* W; int K, N, Kp, kb, nb, fp8;
    short* Wts = nullptr; unsigned char* Wt8 = nullptr;
    if (b < 200)      { W = W_in; Wts = Wt_in; fp8 = 0; K = IND; N = 256; Kp = 800; kb = (b % 25) * 32; nb = (b / 25) * 32; }
    else if (b < 264) { b -= 200; W = W1; Wt8 = Wt1; fp8 = 1; K = 256; N = 256; Kp = 256; kb = (b % 8) * 32; nb = (b / 8) * 32; }
    else if (b < 296) { b -= 264; W = W2; Wt8 = Wt2; fp8 = 1; K = 256; N = 128; Kp = 256; kb = (b % 8) * 32; nb = (b / 8) * 32; }
    else {
        int i = (b - 296) * 256 + threadIdx.x;
        if (i < NN) deg[i] = 0;
        if (i < NB * 128) emb[i] = 0.f;
        return;
    }
    __shared__ float tile[32][33];
    int tx = threadIdx.x & 31, ty = threadIdx.x >> 5;
#pragma unroll
    for (int r = 0; r < 32; r += 8) {
        int k = kb + ty + r;
        tile[ty + r][tx] = (k < K) ? W[(size_t)k * N + nb + tx] : 0.f;
    }
    __syncthreads();
#pragma unroll
    for (int r = 0; r < 32; r += 8) {
        int n = nb + ty + r, k = kb + tx;
        float v = tile[tx][ty + r];
        if (fp8) Wt8[(size_t)n * Kp + k] = enc8(v);
        else     Wts[(size_t)n * Kp + k] = f2b(v);
    }
}

// ---------------- CSR build ----------------
__global__ void k_hist(const int* __restrict__ ei, int* __restrict__ deg) {
    int e = blockIdx.x * 256 + threadIdx.x;
    if (e >= NE) return;
    atomicAdd(&deg[ei[NE + e]], 1);
}

__global__ __launch_bounds__(256) void k_bsum(const int* __restrict__ deg,
                                              int* __restrict__ bsum) {
    int i = blockIdx.x * 256 + threadIdx.x;
    int v = (i < NN) ? deg[i] : 0;
#pragma unroll
    for (int off = 32; off; off >>= 1) v += __shfl_down(v, off);
    __shared__ int ws[4];
    if ((threadIdx.x & 63) == 0) ws[threadIdx.x >> 6] = v;
    __syncthreads();
    if (threadIdx.x == 0) bsum[blockIdx.x] = ws[0] + ws[1] + ws[2] + ws[3];
}

__global__ __launch_bounds__(256) void k_scan3(const int* __restrict__ deg,
                                               const int* __restrict__ bsum,
                                               int* __restrict__ rowp,
                                               int* __restrict__ cursor) {
    int b = blockIdx.x;
    int i = b * 256 + threadIdx.x;
    int d = (i < NN) ? deg[i] : 0;
    __shared__ int sb[SCAN_B];
    if (threadIdx.x < SCAN_B) sb[threadIdx.x] = bsum[threadIdx.x];
    int v = d;
    int lane = threadIdx.x & 63, wid = threadIdx.x >> 6;
#pragma unroll
    for (int off = 1; off < 64; off <<= 1) {
        int u = __shfl_up(v, off);
        if (lane >= off) v += u;
    }
    __shared__ int ws[4];
    if (lane == 63) ws[wid] = v;
    __syncthreads();
    int add = 0;
    for (int q = 0; q < b; ++q) add += sb[q];
    for (int wq = 0; wq < wid; ++wq) add += ws[wq];
    int excl = add + v - d;
    if (i < NN) { rowp[i] = excl; cursor[i] = excl; }
    if (i == NN - 1) rowp[NN] = excl + d;
}

__global__ void k_scatter(const int* __restrict__ ei, int* __restrict__ cursor,
                          int* __restrict__ colidx) {
    int e = blockIdx.x * 256 + threadIdx.x;
    if (e >= NE) return;
    int s = ei[e], d = ei[NE + e];
    int pos = atomicAdd(&cursor[d], 1);
    colidx[pos] = s;
}

// ---------------- fused GAT aggregation, fp8 gather; OUT8: fp8 or bf16 out ----------------
template<int HD, int OUT8>
__global__ __launch_bounds__(256) void gat_agg(const unsigned char* __restrict__ hW8,
                                               const float* __restrict__ a_s,
                                               const float* __restrict__ a_d,
                                               const int* __restrict__ row_ptr,
                                               const int* __restrict__ colidx,
                                               const float* __restrict__ bias,
                                               void* __restrict__ outp) {
    const int CPL = HD / 64;
    int node = blockIdx.x * 4 + (threadIdx.x >> 6);
    int lane = threadIdx.x & 63;
    if (node >= NN) return;
    int h = lane >> 4;
    int start = row_ptr[node], end = row_ptr[node + 1];
    float adst = a_d[node * 4 + h];
    float eself = lrelu(a_s[node * 4 + h] + adst);

    float z = 1.f;
    float acc[CPL];
    {
        const unsigned char* row = hW8 + (size_t)node * HD + lane * CPL;
        if (CPL == 4) dec4(*(const unsigned*)row, acc);
        else          dec2(*(const unsigned short*)row, acc);
    }
    for (int e = start; e < end; e += 8) {
        int sidx[8];
        float xs[8], ex[8];
#pragma unroll
        for (int q = 0; q < 8; ++q) {
            int ee = e + q;
            sidx[q] = colidx[ee < end ? ee : end - 1];
        }
#pragma unroll
        for (int q = 0; q < 8; ++q) xs[q] = a_s[sidx[q] * 4 + h];
        float v[8][CPL];
        if (CPL == 4) {
#pragma unroll
            for (int q = 0; q < 8; ++q)
                dec4(*(const unsigned*)(hW8 + (size_t)sidx[q] * HD + lane * 4), v[q]);
        } else {
#pragma unroll
            for (int q = 0; q < 8; ++q)
                dec2(*(const unsigned short*)(hW8 + (size_t)sidx[q] * HD + lane * 2), v[q]);
        }
#pragma unroll
        for (int q = 0; q < 8; ++q) {
            float wq = __expf(lrelu(xs[q] + adst) - eself);
            ex[q] = (e + q < end) ? wq : 0.f;
        }
#pragma unroll
        for (int q = 0; q < 8; ++q) z += ex[q];
#pragma unroll
        for (int j = 0; j < CPL; ++j) {
            float a = 0.f;
#pragma unroll
            for (int q = 0; q < 8; ++q) a += ex[q] * v[q][j];
            acc[j] += a;
        }
    }
    float inv = 1.f / z;
    float o[CPL];
#pragma unroll
    for (int j = 0; j < CPL; ++j)
        o[j] = fmaxf(acc[j] * inv + bias[lane * CPL + j], 0.f);
    if (OUT8) {
        unsigned* orow = (unsigned*)((unsigned char*)outp + (size_t)node * HD + lane * 4);
        *orow = pack4fp8(o[0], o[1], (CPL == 4 ? o[2] : 0.f), (CPL == 4 ? o[3] : 0.f));
    } else {
        short* orow = (short*)outp + (size_t)node * HD + lane * CPL;
#pragma unroll
        for (int j = 0; j < CPL; ++j) orow[j] = f2b(o[j]);
    }
}

// ---------------- pooling: partial sums (256 blocks) + head ----------------
__global__ __launch_bounds__(128) void k_pool(const short* __restrict__ h2,
                                              const int* __restrict__ batch,
                                              float* __restrict__ emb) {
    int b = blockIdx.x >> 2;
    int chunk = blockIdx.x & 3;
    int t = threadIdx.x;
    int lo = 0, hi = NN;
    while (lo < hi) { int mid = (lo + hi) >> 1; if (batch[mid] < b) lo = mid + 1; else hi = mid; }
    int start = lo;
    lo = 0; hi = NN;
    while (lo < hi) { int mid = (lo + hi) >> 1; if (batch[mid] < b + 1) lo = mid + 1; else hi = mid; }
    int end = lo;
    float s = 0.f;
    for (int n = start + chunk; n < end; n += 4) s += b2f(h2[(size_t)n * 128 + t]);
    atomicAdd(&emb[b * 128 + t], s);
}

__global__ __launch_bounds__(128) void k_head(const float* __restrict__ emb,
                                              const int* __restrict__ batch,
                                              const float* __restrict__ W_cls,
                                              const float* __restrict__ b_cls,
                                              const float* __restrict__ W_conf,
                                              const float* __restrict__ b_conf,
                                              float* __restrict__ out) {
    int b = blockIdx.x;
    int t = threadIdx.x;
    int lo = 0, hi = NN;
    while (lo < hi) { int mid = (lo + hi) >> 1; if (batch[mid] < b) lo = mid + 1; else hi = mid; }
    int start = lo;
    lo = 0; hi = NN;
    while (lo < hi) { int mid = (lo + hi) >> 1; if (batch[mid] < b + 1) lo = mid + 1; else hi = mid; }
    int end = lo;
    __shared__ float se[128];
    se[t] = emb[b * 128 + t] / fmaxf((float)(end - start), 1.f);
    __syncthreads();
    if (t == 0) {
        float v = b_cls[0];
        for (int c = 0; c < 128; ++c) v += se[c] * W_cls[c * 2 + 0];
        out[b * 2 + 0] = v;
    } else if (t == 1) {
        float v = b_cls[1];
        for (int c = 0; c < 128; ++c) v += se[c] * W_cls[c * 2 + 1];
        out[b * 2 + 1] = v;
    } else if (t == 2) {
        float v = b_conf[0];
        for (int c = 0; c < 128; ++c) v += se[c] * W_conf[c];
        out[128 + b] = 1.f / (1.f + expf(-v));
    }
}

extern "C" void kernel_launch(void* const* d_in, const int* in_sizes, int n_in,
                              void* d_out, int out_size, void* d_ws, size_t ws_size,
                              hipStream_t stream) {
    const float* x        = (const float*)d_in[0];
    const int*   ei       = (const int*)d_in[1];
    const int*   batch    = (const int*)d_in[2];
    const float* W_in     = (const float*)d_in[3];
    const float* b_in     = (const float*)d_in[4];
    const float* W1       = (const float*)d_in[5];
    const float* att_src1 = (const float*)d_in[6];
    const float* att_dst1 = (const float*)d_in[7];
    const float* b1       = (const float*)d_in[8];
    const float* W2       = (const float*)d_in[9];
    const float* att_src2 = (const float*)d_in[10];
    const float* att_dst2 = (const float*)d_in[11];
    const float* b2       = (const float*)d_in[12];
    const float* W_cls    = (const float*)d_in[13];
    const float* b_cls    = (const float*)d_in[14];
    const float* W_conf   = (const float*)d_in[15];
    const float* b_conf   = (const float*)d_in[16];
    float* out = (float*)d_out;

    char* ws = (char*)d_ws;
    unsigned char* h0  = (unsigned char*)(ws + 0);          // [MPAD][256] fp8
    unsigned char* hW1 = (unsigned char*)(ws + 12812288);   // [MPAD][256] fp8
    unsigned char* h1  = (unsigned char*)(ws + 25624576);   // [MPAD][256] fp8
    unsigned char* hW2 = (unsigned char*)(ws + 38436864);   // [MPAD][128] fp8
    short*         h2  = (short*)(ws + 44843008);           // [MPAD][128] bf16
    size_t base = 57655296;
    short*         Wt_in = (short*)(ws + base);                   // [256][800] bf16
    unsigned char* Wt1   = (unsigned char*)(ws + base + 409600);  // [256][256] fp8
    unsigned char* Wt2   = (unsigned char*)(ws + base + 475136);  // [128][256] fp8
    float* a_s1  = (float*)(ws + base + 507904);
    float* a_d1  = (float*)(ws + base + 1307904);
    float* emb   = (float*)(ws + base + 2107904);   // [64][128]
    int*   deg    = (int*)(ws + base + 2140672);
    int*   rowp   = (int*)(ws + base + 2340672);
    int*   cursor = (int*)(ws + base + 2540736);
    int*   colidx = (int*)(ws + base + 2740736);    // [800000]
    int*   bsum   = (int*)(ws + base + 5940736);

    // prep: weight transposes (bf16 + fp8) + deg/emb zero
    k_prep<<<296 + SCAN_B, 256, 0, stream>>>(W_in, W1, W2, Wt_in, Wt1, Wt2, deg, emb);
    // CSR build
    k_hist<<<NE / 256, 256, 0, stream>>>(ei, deg);
    k_bsum<<<SCAN_B, 256, 0, stream>>>(deg, bsum);
    k_scan3<<<SCAN_B, 256, 0, stream>>>(deg, bsum, rowp, cursor);
    k_scatter<<<NE / 256, 256, 0, stream>>>(ei, cursor, colidx);

    // h0(fp8) = relu(x @ W_in + b_in)
    gemm_a<<<391, 512, 0, stream>>>(x, Wt_in, b_in, h0);
    // hW1(fp8) = h0 @ W1 (fp8 MFMA), att dots fused
    gemm_b<<<dim3(391, 2), 256, 0, stream>>>(h0, Wt1, att_src1, att_dst1, hW1, a_s1, a_d1);
    gat_agg<256, 1><<<12500, 256, 0, stream>>>(hW1, a_s1, a_d1, rowp, colidx, b1, h1);
    // hW2(fp8) = h1 @ W2 (fp8 MFMA), att dots fused
    gemm_c<<<391, 256, 0, stream>>>(h1, Wt2, att_src2, att_dst2, hW2, a_s1, a_d1);
    gat_agg<128, 0><<<12500, 256, 0, stream>>>(hW2, a_s1, a_d1, rowp, colidx, b2, h2);
    // pool + heads
    k_pool<<<NB * 4, 128, 0, stream>>>(h2, batch, emb);
    k_head<<<NB, 128, 0, stream>>>(emb, batch, W_cls, b_cls, W_conf, b_conf, out);
}